// Round 1
// baseline (1512.412 us; speedup 1.0000x reference)
//
#include <hip/hip_runtime.h>
#include <math.h>

// Problem constants
#define BATCH 512
#define DIM   512
#define NH    16
#define DH    32
#define NPOS  251   // cross-attn positions
#define TPOS  256   // self-attn cached positions (K1 has TPOS+1)
#define BD    (BATCH * DIM)

// ---------------------------------------------------------------------------
// wave-wide butterfly reductions (all 64 lanes end with the result)
// ---------------------------------------------------------------------------
__device__ __forceinline__ float red_add64(float v) {
#pragma unroll
    for (int m = 32; m; m >>= 1) v += __shfl_xor(v, m);
    return v;
}
__device__ __forceinline__ float red_max64(float v) {
#pragma unroll
    for (int m = 32; m; m >>= 1) v = fmaxf(v, __shfl_xor(v, m));
    return v;
}

// ---------------------------------------------------------------------------
// Tiled fp32 GEMM: out(512x512) = X(512x512) @ W(512x512) + bias [+ relu]
// 64x64 tile per block, 256 threads, 4x4 micro-tile per thread.
// ---------------------------------------------------------------------------
__device__ __forceinline__ void gemm_body(const float* __restrict__ X,
                                          const float* __restrict__ W,
                                          const float* __restrict__ bias,
                                          float* __restrict__ out, int relu) {
    __shared__ float As[32][68];  // transposed: As[k][m]
    __shared__ float Bs[32][68];  // Bs[k][n]
    const int tid = threadIdx.x;
    const int r0 = blockIdx.y * 64;
    const int c0 = blockIdx.x * 64;
    const int ty = tid >> 4, tx = tid & 15;
    float acc[4][4] = {};

    for (int k0 = 0; k0 < 512; k0 += 32) {
#pragma unroll
        for (int rep = 0; rep < 2; rep++) {
            int idx = tid + rep * 256;
            int ai = idx >> 3, aj = idx & 7;
            float4 a = *reinterpret_cast<const float4*>(X + (size_t)(r0 + ai) * 512 + k0 + aj * 4);
            As[aj * 4 + 0][ai] = a.x;
            As[aj * 4 + 1][ai] = a.y;
            As[aj * 4 + 2][ai] = a.z;
            As[aj * 4 + 3][ai] = a.w;
            int bk = idx >> 4, bn = idx & 15;
            *reinterpret_cast<float4*>(&Bs[bk][bn * 4]) =
                *reinterpret_cast<const float4*>(W + (size_t)(k0 + bk) * 512 + c0 + bn * 4);
        }
        __syncthreads();
#pragma unroll
        for (int kk = 0; kk < 32; kk++) {
            float4 a = *reinterpret_cast<const float4*>(&As[kk][ty * 4]);
            float4 b = *reinterpret_cast<const float4*>(&Bs[kk][tx * 4]);
            float av[4] = {a.x, a.y, a.z, a.w};
            float bv[4] = {b.x, b.y, b.z, b.w};
#pragma unroll
            for (int i = 0; i < 4; i++)
#pragma unroll
                for (int j = 0; j < 4; j++) acc[i][j] += av[i] * bv[j];
        }
        __syncthreads();
    }
    float4 bz = *reinterpret_cast<const float4*>(bias + c0 + tx * 4);
    float bzv[4] = {bz.x, bz.y, bz.z, bz.w};
#pragma unroll
    for (int i = 0; i < 4; i++) {
        float4 v;
        v.x = acc[i][0] + bzv[0];
        v.y = acc[i][1] + bzv[1];
        v.z = acc[i][2] + bzv[2];
        v.w = acc[i][3] + bzv[3];
        if (relu) {
            v.x = fmaxf(v.x, 0.f); v.y = fmaxf(v.y, 0.f);
            v.z = fmaxf(v.z, 0.f); v.w = fmaxf(v.w, 0.f);
        }
        *reinterpret_cast<float4*>(out + (size_t)(r0 + ty * 4 + i) * 512 + c0 + tx * 4) = v;
    }
}

__global__ __launch_bounds__(256) void gemm_bias(const float* __restrict__ X,
                                                 const float* __restrict__ W,
                                                 const float* __restrict__ bias,
                                                 float* __restrict__ out, int relu) {
    gemm_body(X, W, bias, out, relu);
}

// fused q/k/v projection: blockIdx.z selects matrix
__global__ __launch_bounds__(256) void gemm_qkv(const float* __restrict__ X,
                                                const float* __restrict__ Wq,
                                                const float* __restrict__ Wk,
                                                const float* __restrict__ Wv,
                                                const float* __restrict__ bq,
                                                const float* __restrict__ bk,
                                                const float* __restrict__ bv,
                                                float* __restrict__ oq,
                                                float* __restrict__ ok,
                                                float* __restrict__ ov) {
    const float* W; const float* bias; float* out;
    if (blockIdx.z == 0) { W = Wq; bias = bq; out = oq; }
    else if (blockIdx.z == 1) { W = Wk; bias = bk; out = ok; }
    else { W = Wv; bias = bv; out = ov; }
    gemm_body(X, W, bias, out, 0);
}

// ---------------------------------------------------------------------------
// residual + LayerNorm: out = g * ((A+T) - mean)/sqrt(var+eps) + b, per row
// one wave per row, 4 rows per block
// ---------------------------------------------------------------------------
__global__ __launch_bounds__(256) void ln_res(const float* __restrict__ A,
                                              const float* __restrict__ Tm,
                                              const float* __restrict__ g,
                                              const float* __restrict__ bb,
                                              float* __restrict__ out) {
    const int w = threadIdx.x >> 6, l = threadIdx.x & 63;
    const size_t r = (size_t)blockIdx.x * 4 + w;
    const float* a = A + r * 512;
    const float* t = Tm + r * 512;
    float4 a0 = *reinterpret_cast<const float4*>(a + l * 4);
    float4 t0 = *reinterpret_cast<const float4*>(t + l * 4);
    float4 a1 = *reinterpret_cast<const float4*>(a + 256 + l * 4);
    float4 t1 = *reinterpret_cast<const float4*>(t + 256 + l * 4);
    float4 y0 = {a0.x + t0.x, a0.y + t0.y, a0.z + t0.z, a0.w + t0.w};
    float4 y1 = {a1.x + t1.x, a1.y + t1.y, a1.z + t1.z, a1.w + t1.w};
    float s = y0.x + y0.y + y0.z + y0.w + y1.x + y1.y + y1.z + y1.w;
    s = red_add64(s);
    const float mean = s * (1.f / 512.f);
    float vs = (y0.x - mean) * (y0.x - mean) + (y0.y - mean) * (y0.y - mean) +
               (y0.z - mean) * (y0.z - mean) + (y0.w - mean) * (y0.w - mean) +
               (y1.x - mean) * (y1.x - mean) + (y1.y - mean) * (y1.y - mean) +
               (y1.z - mean) * (y1.z - mean) + (y1.w - mean) * (y1.w - mean);
    vs = red_add64(vs);
    const float rinv = rsqrtf(vs * (1.f / 512.f) + 1e-5f);
    float4 g0 = *reinterpret_cast<const float4*>(g + l * 4);
    float4 b0 = *reinterpret_cast<const float4*>(bb + l * 4);
    float4 g1 = *reinterpret_cast<const float4*>(g + 256 + l * 4);
    float4 b1 = *reinterpret_cast<const float4*>(bb + 256 + l * 4);
    float4 o0 = {g0.x * (y0.x - mean) * rinv + b0.x, g0.y * (y0.y - mean) * rinv + b0.y,
                 g0.z * (y0.z - mean) * rinv + b0.z, g0.w * (y0.w - mean) * rinv + b0.w};
    float4 o1 = {g1.x * (y1.x - mean) * rinv + b1.x, g1.y * (y1.y - mean) * rinv + b1.y,
                 g1.z * (y1.z - mean) * rinv + b1.z, g1.w * (y1.w - mean) * rinv + b1.w};
    *reinterpret_cast<float4*>(out + r * 512 + l * 4) = o0;
    *reinterpret_cast<float4*>(out + r * 512 + 256 + l * 4) = o1;
}

// ---------------------------------------------------------------------------
// Self-attention (16 heads, dh=32) over K1 = [K_sa ; k_sa] (257 positions).
// grid (BATCH, 2): each block owns 8 heads = 256 contiguous dims.
// Each wave handles one position per iteration (64 lanes x float4 = 256 floats).
// ---------------------------------------------------------------------------
__global__ __launch_bounds__(256) void attn_self(const float* __restrict__ q_sa,
                                                 const float* __restrict__ k_sa,
                                                 const float* __restrict__ v_sa,
                                                 const float* __restrict__ K_sa,
                                                 const float* __restrict__ V_sa,
                                                 float* __restrict__ sa_out) {
    const int b = blockIdx.x;
    const int hg = blockIdx.y;  // head group 0..1
    const int tid = threadIdx.x;
    const int w = tid >> 6, l = tid & 63;
    const int d = hg * 256 + l * 4;
    const int hidx = l >> 3;  // head within group

    __shared__ float sc[8][260];
    __shared__ float ssum[8];
    __shared__ float outb[4][256];

    const float4 q4 = *reinterpret_cast<const float4*>(q_sa + (size_t)b * 512 + d);
    const float* Kb = K_sa + (size_t)b * TPOS * 512;
    const float* Vb = V_sa + (size_t)b * TPOS * 512;
    const float scale = 0.17677669529663687f;  // 1/sqrt(32)

    // scores
#pragma unroll 2
    for (int p = w; p < TPOS + 1; p += 4) {
        const float* krow = (p < TPOS) ? (Kb + (size_t)p * 512) : (k_sa + (size_t)b * 512);
        float4 k4 = *reinterpret_cast<const float4*>(krow + d);
        float s = q4.x * k4.x + q4.y * k4.y + q4.z * k4.z + q4.w * k4.w;
        s += __shfl_xor(s, 1);
        s += __shfl_xor(s, 2);
        s += __shfl_xor(s, 4);
        if ((l & 7) == 0) sc[hidx][p] = s * scale;
    }
    __syncthreads();

    // softmax per head (unnormalized exp kept; sum stored)
    for (int h = w; h < 8; h += 4) {
        float v[5];
        float m = -1e30f;
#pragma unroll
        for (int c = 0; c < 5; c++) {
            int idx = c * 64 + l;
            v[c] = (idx < TPOS + 1) ? sc[h][idx] : -1e30f;
            m = fmaxf(m, v[c]);
        }
        m = red_max64(m);
        float s = 0.f;
#pragma unroll
        for (int c = 0; c < 5; c++) {
            int idx = c * 64 + l;
            float e = __expf(v[c] - m);
            if (idx < TPOS + 1) { sc[h][idx] = e; s += e; }
        }
        s = red_add64(s);
        if (l == 0) ssum[h] = s;
    }
    __syncthreads();

    // PV
    float4 acc = {0.f, 0.f, 0.f, 0.f};
#pragma unroll 2
    for (int p = w; p < TPOS + 1; p += 4) {
        const float* vrow = (p < TPOS) ? (Vb + (size_t)p * 512) : (v_sa + (size_t)b * 512);
        float4 v4 = *reinterpret_cast<const float4*>(vrow + d);
        float e = sc[hidx][p];
        acc.x += e * v4.x; acc.y += e * v4.y; acc.z += e * v4.z; acc.w += e * v4.w;
    }
    *reinterpret_cast<float4*>(&outb[w][l * 4]) = acc;
    __syncthreads();
    if (tid < 64) {
        float4 r = {0.f, 0.f, 0.f, 0.f};
#pragma unroll
        for (int ww = 0; ww < 4; ww++) {
            float4 t = *reinterpret_cast<const float4*>(&outb[ww][tid * 4]);
            r.x += t.x; r.y += t.y; r.z += t.z; r.w += t.w;
        }
        const float inv = 1.f / ssum[tid >> 3];
        r.x *= inv; r.y *= inv; r.z *= inv; r.w *= inv;
        *reinterpret_cast<float4*>(sa_out + (size_t)b * 512 + hg * 256 + tid * 4) = r;
    }
}

// ---------------------------------------------------------------------------
// Cross-attention (16 heads, dh=32, masked) over K_att[:,:,0:512]/V_att[:,:,0:512]
// grid (BATCH, 2)
// ---------------------------------------------------------------------------
__global__ __launch_bounds__(256) void attn_cross(const float* __restrict__ q_a,
                                                  const float* __restrict__ K_att,
                                                  const float* __restrict__ V_att,
                                                  const int* __restrict__ mask,
                                                  float* __restrict__ a_out) {
    const int b = blockIdx.x;
    const int hg = blockIdx.y;
    const int tid = threadIdx.x;
    const int w = tid >> 6, l = tid & 63;
    const int d = hg * 256 + l * 4;
    const int hidx = l >> 3;

    __shared__ float sc[8][256];
    __shared__ float ssum[8];
    __shared__ float outb[4][256];

    const float4 q4 = *reinterpret_cast<const float4*>(q_a + (size_t)b * 512 + d);
    const float scale = 0.17677669529663687f;  // 1/sqrt(32)

#pragma unroll 2
    for (int p = w; p < NPOS; p += 4) {
        const float* krow = K_att + ((size_t)b * NPOS + p) * 1024;
        const bool mp = mask[(size_t)b * NPOS + p] != 0;
        float4 k4 = *reinterpret_cast<const float4*>(krow + d);
        float s = q4.x * k4.x + q4.y * k4.y + q4.z * k4.z + q4.w * k4.w;
        s += __shfl_xor(s, 1);
        s += __shfl_xor(s, 2);
        s += __shfl_xor(s, 4);
        if ((l & 7) == 0) sc[hidx][p] = mp ? -1e9f : s * scale;
    }
    __syncthreads();

    for (int h = w; h < 8; h += 4) {
        float v[4];
        float m = -1e30f;
#pragma unroll
        for (int c = 0; c < 4; c++) {
            int idx = c * 64 + l;
            v[c] = (idx < NPOS) ? sc[h][idx] : -1e30f;
            m = fmaxf(m, v[c]);
        }
        m = red_max64(m);
        float s = 0.f;
#pragma unroll
        for (int c = 0; c < 4; c++) {
            int idx = c * 64 + l;
            float e = __expf(v[c] - m);
            if (idx < NPOS) { sc[h][idx] = e; s += e; }
        }
        s = red_add64(s);
        if (l == 0) ssum[h] = s;
    }
    __syncthreads();

    float4 acc = {0.f, 0.f, 0.f, 0.f};
#pragma unroll 2
    for (int p = w; p < NPOS; p += 4) {
        const float* vrow = V_att + ((size_t)b * NPOS + p) * 1024;
        float4 v4 = *reinterpret_cast<const float4*>(vrow + d);
        float e = sc[hidx][p];
        acc.x += e * v4.x; acc.y += e * v4.y; acc.z += e * v4.z; acc.w += e * v4.w;
    }
    *reinterpret_cast<float4*>(&outb[w][l * 4]) = acc;
    __syncthreads();
    if (tid < 64) {
        float4 r = {0.f, 0.f, 0.f, 0.f};
#pragma unroll
        for (int ww = 0; ww < 4; ww++) {
            float4 t = *reinterpret_cast<const float4*>(&outb[ww][tid * 4]);
            r.x += t.x; r.y += t.y; r.z += t.z; r.w += t.w;
        }
        const float inv = 1.f / ssum[tid >> 3];
        r.x *= inv; r.y *= inv; r.z *= inv; r.w *= inv;
        *reinterpret_cast<float4*>(a_out + (size_t)b * 512 + hg * 256 + tid * 4) = r;
    }
}

// ---------------------------------------------------------------------------
// Final single-head attention over K_att[:,:,512:1024]; returns softmax weights.
// scores = 10*tanh(qf.K/sqrt(512)); mask -> -1e9; softmax over 251.
// grid (BATCH); one wave per position; V never read (output discarded).
// ---------------------------------------------------------------------------
__global__ __launch_bounds__(256) void attn_final(const float* __restrict__ qf,
                                                  const float* __restrict__ K_att,
                                                  const int* __restrict__ mask,
                                                  float* __restrict__ out) {
    const int b = blockIdx.x;
    const int tid = threadIdx.x;
    const int w = tid >> 6, l = tid & 63;

    __shared__ float sc[256];
    __shared__ float red[1];

    const float* q = qf + (size_t)b * 512;
    const float4 qa = *reinterpret_cast<const float4*>(q + l * 4);
    const float4 qb = *reinterpret_cast<const float4*>(q + 256 + l * 4);

#pragma unroll 2
    for (int p = w; p < NPOS; p += 4) {
        const float* krow = K_att + ((size_t)b * NPOS + p) * 1024 + 512;
        float4 ka = *reinterpret_cast<const float4*>(krow + l * 4);
        float4 kb = *reinterpret_cast<const float4*>(krow + 256 + l * 4);
        float s = qa.x * ka.x + qa.y * ka.y + qa.z * ka.z + qa.w * ka.w +
                  qb.x * kb.x + qb.y * kb.y + qb.z * kb.z + qb.w * kb.w;
        s = red_add64(s);
        if (l == 0) {
            s *= 0.044194173824159216f;  // 1/sqrt(512)
            s = 10.f * tanhf(s);
            if (mask[(size_t)b * NPOS + p] != 0) s = -1e9f;
            sc[p] = s;
        }
    }
    __syncthreads();

    if (w == 0) {
        float v[4];
        float m = -1e30f;
#pragma unroll
        for (int c = 0; c < 4; c++) {
            int idx = c * 64 + l;
            v[c] = (idx < NPOS) ? sc[idx] : -1e30f;
            m = fmaxf(m, v[c]);
        }
        m = red_max64(m);
        float s = 0.f;
#pragma unroll
        for (int c = 0; c < 4; c++) {
            int idx = c * 64 + l;
            float e = __expf(v[c] - m);
            if (idx < NPOS) { sc[idx] = e; s += e; }
        }
        s = red_add64(s);
        if (l == 0) red[0] = s;
    }
    __syncthreads();
    const float inv = 1.f / red[0];
    if (tid < NPOS) out[(size_t)b * NPOS + tid] = sc[tid] * inv;
}

// ---------------------------------------------------------------------------
extern "C" void kernel_launch(void* const* d_in, const int* in_sizes, int n_in,
                              void* d_out, int out_size, void* d_ws, size_t ws_size,
                              hipStream_t stream) {
    (void)in_sizes; (void)n_in; (void)out_size; (void)ws_size;
    const float* h_t   = (const float*)d_in[0];
    const float* K_att = (const float*)d_in[1];
    const float* V_att = (const float*)d_in[2];
    const float* K_sa  = (const float*)d_in[3];
    const float* V_sa  = (const float*)d_in[4];
    const float* Wq_sa = (const float*)d_in[5];
    const float* Wk_sa = (const float*)d_in[6];
    const float* Wv_sa = (const float*)d_in[7];
    const float* W0_sa = (const float*)d_in[8];
    const float* Wq_a  = (const float*)d_in[9];
    const float* W0_a  = (const float*)d_in[10];
    const float* W1    = (const float*)d_in[11];
    const float* W2    = (const float*)d_in[12];
    const float* Wqf   = (const float*)d_in[13];
    const float* bq_sa = (const float*)d_in[14];
    const float* bk_sa = (const float*)d_in[15];
    const float* bv_sa = (const float*)d_in[16];
    const float* b0_sa = (const float*)d_in[17];
    const float* bq_a  = (const float*)d_in[18];
    const float* b0_a  = (const float*)d_in[19];
    const float* b1    = (const float*)d_in[20];
    const float* b2    = (const float*)d_in[21];
    const float* bqf   = (const float*)d_in[22];
    const float* ln1_g = (const float*)d_in[23];
    const float* ln2_g = (const float*)d_in[24];
    const float* ln3_g = (const float*)d_in[25];
    const float* ln1_b = (const float*)d_in[26];
    const float* ln2_b = (const float*)d_in[27];
    const float* ln3_b = (const float*)d_in[28];
    const int*   mask  = (const int*)d_in[29];

    float* ws = (float*)d_ws;
    float* s0 = ws + 0 * (size_t)BD;
    float* s1 = ws + 1 * (size_t)BD;
    float* s2 = ws + 2 * (size_t)BD;
    float* s3 = ws + 3 * (size_t)BD;
    float* s4 = ws + 4 * (size_t)BD;
    float* s5 = ws + 5 * (size_t)BD;

    const dim3 blk(256);
    const dim3 g88(8, 8, 1);

    // q_sa(s0), k_sa(s1), v_sa(s2)
    gemm_qkv<<<dim3(8, 8, 3), blk, 0, stream>>>(h_t, Wq_sa, Wk_sa, Wv_sa,
                                                bq_sa, bk_sa, bv_sa, s0, s1, s2);
    // sa_out(s3)
    attn_self<<<dim3(BATCH, 2), blk, 0, stream>>>(s0, s1, s2, K_sa, V_sa, s3);
    // t0(s4) = sa_out @ W0_sa + b0_sa
    gemm_bias<<<g88, blk, 0, stream>>>(s3, W0_sa, b0_sa, s4, 0);
    // x1(s5) = LN1(h_t + t0)
    ln_res<<<dim3(BATCH / 4), blk, 0, stream>>>(h_t, s4, ln1_g, ln1_b, s5);
    // q_a(s0) = x1 @ Wq_a + bq_a
    gemm_bias<<<g88, blk, 0, stream>>>(s5, Wq_a, bq_a, s0, 0);
    // a_out(s1)
    attn_cross<<<dim3(BATCH, 2), blk, 0, stream>>>(s0, K_att, V_att, mask, s1);
    // t1(s2) = a_out @ W0_a + b0_a
    gemm_bias<<<g88, blk, 0, stream>>>(s1, W0_a, b0_a, s2, 0);
    // x2(s3) = LN2(x1 + t1)
    ln_res<<<dim3(BATCH / 4), blk, 0, stream>>>(s5, s2, ln2_g, ln2_b, s3);
    // u(s4) = relu(x2 @ W1 + b1)
    gemm_bias<<<g88, blk, 0, stream>>>(s3, W1, b1, s4, 1);
    // t2(s0) = u @ W2 + b2
    gemm_bias<<<g88, blk, 0, stream>>>(s4, W2, b2, s0, 0);
    // x3(s1) = LN3(x2 + t2)
    ln_res<<<dim3(BATCH / 4), blk, 0, stream>>>(s3, s0, ln3_g, ln3_b, s1);
    // qf(s2) = x3 @ Wqf + bqf
    gemm_bias<<<g88, blk, 0, stream>>>(s1, Wqf, bqf, s2, 0);
    // output weights
    attn_final<<<dim3(BATCH), blk, 0, stream>>>(s2, K_att, mask, (float*)d_out);
}